// Round 7
// baseline (475.677 us; speedup 1.0000x reference)
//
#include <hip/hip_runtime.h>
#include <math.h>

#define EPS 1e-8f

constexpr int B = 64;
constexpr int N = 65536;
constexpr int M = 64;
constexpr int D = 256;
constexpr int A = M + 6; // 70

typedef float vfloat4 __attribute__((ext_vector_type(4)));

// ---- workspace layout (in floats) ----
constexpr size_t OFF_SCAL = 0;                               // [B*8]
constexpr size_t OFF_E    = OFF_SCAL + (size_t)B * 8;        // [B*N]  e = exp(beta*sim)
constexpr size_t OFF_ZP   = OFF_E + (size_t)B * N;           // [B*64] Z partials
constexpr size_t OFF_SP   = OFF_ZP + (size_t)B * 64;         // [B*64] wp-sum partials
constexpr size_t OFF_RP   = OFF_SP + (size_t)B * 64;         // [B*64*M] read partials
// total ~ 4.47M floats ~ 17.9 MB

__device__ __forceinline__ float softplusf(float x) {
    return (x > 20.0f) ? x : log1pf(expf(x));
}

// K2: controller inlined (each block recomputes kn/beta for its batch; block
// bx==0 persists scal for k45). Then e[b,n] = exp(beta * cos_sim(kn, mem_row));
// block partial sums -> zpart. |beta*sim| <= beta (cosine) so no max-subtract.
// nt loads on mem: single-use stream, keep caches for e/wprev/wout.
__global__ void k2_sim(const float* __restrict__ mem,
                       const float* __restrict__ emb,
                       const float* __restrict__ Wm,
                       const float* __restrict__ bias,
                       float* __restrict__ e,
                       float* __restrict__ zpart,
                       float* __restrict__ scal) {
    const int ROWS = 1024;
    int b = blockIdx.y;
    int base = blockIdx.x * ROWS;
    int t = threadIdx.x; // 256
    int gid = t >> 4, q = t & 15;

    // ---- inline controller ----
    __shared__ float se[D];
    __shared__ float sa[A];
    __shared__ float s_kn[M];
    __shared__ float s_beta;
    se[t] = emb[(size_t)b * D + t];
    __syncthreads();
    if (t < A) {
        float acc = bias[t];
        #pragma unroll 8
        for (int d = 0; d < D; ++d) acc += se[d] * Wm[(size_t)d * A + t];
        sa[t] = acc;
    }
    __syncthreads();
    if (t == 0) {
        float s = 0.f;
        for (int j = 0; j < M; ++j) s += sa[j] * sa[j];
        float snorm = sqrtf(s) + EPS;
        float beta = softplusf(sa[M]);
        s_beta = beta;
        for (int j = 0; j < M; ++j) s_kn[j] = sa[j] / snorm;
        if (blockIdx.x == 0) {
            float g = 1.f / (1.f + expf(-sa[M + 1]));
            float s0 = sa[M + 2], s1 = sa[M + 3], s2 = sa[M + 4];
            float mx = fmaxf(s0, fmaxf(s1, s2));
            float e0 = expf(s0 - mx), e1 = expf(s1 - mx), e2 = expf(s2 - mx);
            float Zs = e0 + e1 + e2;
            float gamma = 1.f + softplusf(sa[M + 5]);
            scal[b * 8 + 0] = beta;
            scal[b * 8 + 1] = g;
            scal[b * 8 + 2] = e0 / Zs;
            scal[b * 8 + 3] = e1 / Zs;
            scal[b * 8 + 4] = e2 / Zs;
            scal[b * 8 + 5] = gamma;
        }
    }
    __syncthreads();
    float beta = s_beta;
    vfloat4 knq;
    knq.x = s_kn[q * 4 + 0];
    knq.y = s_kn[q * 4 + 1];
    knq.z = s_kn[q * 4 + 2];
    knq.w = s_kn[q * 4 + 3];

    // ---- stream mem ----
    const vfloat4* mrow = reinterpret_cast<const vfloat4*>(mem + (size_t)b * N * M);
    float* eb = e + (size_t)b * N;
    float lsum = 0.f;
    #pragma unroll 8
    for (int r = gid; r < ROWS; r += 16) {
        int n = base + r;
        vfloat4 v = __builtin_nontemporal_load(&mrow[(size_t)n * 16 + q]);
        float dot = v.x * knq.x + v.y * knq.y + v.z * knq.z + v.w * knq.w;
        float nrm = v.x * v.x + v.y * v.y + v.z * v.z + v.w * v.w;
        #pragma unroll
        for (int msk = 8; msk >= 1; msk >>= 1) {
            dot += __shfl_xor(dot, msk);
            nrm += __shfl_xor(nrm, msk);
        }
        float ev = expf(beta * (dot / (sqrtf(nrm) + EPS)));
        if (q == 0) { eb[n] = ev; lsum += ev; }
    }
    __shared__ float red[16];
    if (q == 0) red[gid] = lsum;
    __syncthreads();
    if (t == 0) {
        float s = 0.f;
        #pragma unroll
        for (int i = 0; i < 16; ++i) s += red[i];
        zpart[b * 64 + blockIdx.x] = s;
    }
}

// K45: phase 1 computes wp (stencil+pow, unnormalized) for this block's 1024 rows
// into LDS + wout (vectorized). Phase 2 streams mem once: read partials += wp*row.
__global__ void k45_fused(const float* __restrict__ mem,
                          const float* __restrict__ e,
                          const float* __restrict__ wprev,
                          const float* __restrict__ scal,
                          const float* __restrict__ zpart,
                          float* __restrict__ wout,
                          float* __restrict__ spart,
                          float* __restrict__ readpart) {
    const int ROWS = 1024;
    int b = blockIdx.y;
    int bx = blockIdx.x; // 64
    int base = bx * ROWS;
    int t = threadIdx.x; // 256
    int gid = t >> 4, q = t & 15;

    __shared__ float s_wp[ROWS];
    __shared__ float red[256];
    __shared__ float sacc[16][64];

    float Z = 0.f;
    const float* zp = zpart + b * 64;
    #pragma unroll
    for (int i = 0; i < 64; ++i) Z += zp[i];
    float g   = scal[b * 8 + 1];
    float s0  = scal[b * 8 + 2];
    float s1  = scal[b * 8 + 3];
    float s2  = scal[b * 8 + 4];
    float gam = scal[b * 8 + 5];
    float c1 = g / Z;
    float c2 = 1.f - g;

    const float* eb = e + (size_t)b * N;
    const float* wb = wprev + (size_t)b * N;
    float* wo = wout + (size_t)b * N;

    // ---- phase 1: wp for rows [base, base+1024), 4 rows/thread ----
    {
        int n0 = base + t * 4;
        vfloat4 e4 = *reinterpret_cast<const vfloat4*>(eb + n0);
        vfloat4 w4 = *reinterpret_cast<const vfloat4*>(wb + n0);
        int nm = (n0 - 1) & (N - 1);
        int np = (n0 + 4) & (N - 1);
        float em = eb[nm], ep = eb[np];
        float wm = wb[nm], wpp = wb[np];
        float wgm = c1 * em   + c2 * wm;
        float wg0 = c1 * e4.x + c2 * w4.x;
        float wg1 = c1 * e4.y + c2 * w4.y;
        float wg2 = c1 * e4.z + c2 * w4.z;
        float wg3 = c1 * e4.w + c2 * w4.w;
        float wg4 = c1 * ep   + c2 * wpp;
        float p0 = powf(s0 * wgm + s1 * wg0 + s2 * wg1, gam);
        float p1 = powf(s0 * wg0 + s1 * wg1 + s2 * wg2, gam);
        float p2 = powf(s0 * wg1 + s1 * wg2 + s2 * wg3, gam);
        float p3 = powf(s0 * wg2 + s1 * wg3 + s2 * wg4, gam);
        s_wp[t * 4 + 0] = p0;
        s_wp[t * 4 + 1] = p1;
        s_wp[t * 4 + 2] = p2;
        s_wp[t * 4 + 3] = p3;
        vfloat4 pv; pv.x = p0; pv.y = p1; pv.z = p2; pv.w = p3;
        *reinterpret_cast<vfloat4*>(wo + n0) = pv;
        red[t] = (p0 + p1) + (p2 + p3);
    }
    __syncthreads();

    // ---- phase 2: stream mem, accumulate wp * row ----
    const vfloat4* mrow = reinterpret_cast<const vfloat4*>(mem + (size_t)b * N * M);
    vfloat4 acc = (vfloat4)0.f;
    #pragma unroll 8
    for (int r = gid; r < ROWS; r += 16) {
        float wp = s_wp[r];
        vfloat4 v = __builtin_nontemporal_load(&mrow[(size_t)(base + r) * 16 + q]);
        acc.x += wp * v.x;
        acc.y += wp * v.y;
        acc.z += wp * v.z;
        acc.w += wp * v.w;
    }
    sacc[gid][q * 4 + 0] = acc.x;
    sacc[gid][q * 4 + 1] = acc.y;
    sacc[gid][q * 4 + 2] = acc.z;
    sacc[gid][q * 4 + 3] = acc.w;
    __syncthreads();
    if (t < 64) {
        float s = 0.f;
        #pragma unroll
        for (int g2 = 0; g2 < 16; ++g2) s += sacc[g2][t];
        readpart[((size_t)b * 64 + bx) * 64 + t] = s;
    }
    // spart = sum of wp over this block's rows
    for (int k = 128; k >= 1; k >>= 1) {
        if (t < k) red[t] += red[t + k];
        __syncthreads();
    }
    if (t == 0) spart[b * 64 + bx] = red[0];
}

// K67: bx<64: w *= invS (float4). bx==64: read[b,m] = sum(partials)*invS.
__global__ void k67_epilogue(float* __restrict__ wout,
                             const float* __restrict__ spart,
                             const float* __restrict__ readpart,
                             float* __restrict__ readout) {
    int b = blockIdx.y;
    int bx = blockIdx.x; // 0..64
    int t = threadIdx.x; // 256
    float S = 0.f;
    const float* sp = spart + b * 64;
    #pragma unroll
    for (int i = 0; i < 64; ++i) S += sp[i];
    float invS = 1.f / (S + EPS);
    if (bx < 64) {
        size_t idx = (size_t)b * (N / 4) + (size_t)bx * 256 + t;
        vfloat4* w4 = reinterpret_cast<vfloat4*>(wout);
        vfloat4 v = w4[idx];
        v.x *= invS; v.y *= invS; v.z *= invS; v.w *= invS;
        w4[idx] = v;
    } else if (t < 64) {
        float s = 0.f;
        #pragma unroll
        for (int kb = 0; kb < 64; ++kb) s += readpart[((size_t)b * 64 + kb) * 64 + t];
        readout[b * 64 + t] = s * invS;
    }
}

extern "C" void kernel_launch(void* const* d_in, const int* in_sizes, int n_in,
                              void* d_out, int out_size, void* d_ws, size_t ws_size,
                              hipStream_t stream) {
    const float* emb   = (const float*)d_in[0];
    const float* wprev = (const float*)d_in[1];
    const float* mem   = (const float*)d_in[2];
    const float* Wm    = (const float*)d_in[3];
    const float* bias  = (const float*)d_in[4];

    float* out = (float*)d_out;
    float* readout = out;                 // [B, M]
    float* wout    = out + (size_t)B * M; // [B, N]

    float* ws = (float*)d_ws;
    float* scal = ws + OFF_SCAL;
    float* e    = ws + OFF_E;
    float* zp   = ws + OFF_ZP;
    float* sp   = ws + OFF_SP;
    float* rp   = ws + OFF_RP;

    k2_sim<<<dim3(64, B), dim3(256), 0, stream>>>(mem, emb, Wm, bias, e, zp, scal);
    k45_fused<<<dim3(64, B), dim3(256), 0, stream>>>(mem, e, wprev, scal, zp,
                                                     wout, sp, rp);
    k67_epilogue<<<dim3(65, B), dim3(256), 0, stream>>>(wout, sp, rp, readout);
}

// Round 8
// 390.045 us; speedup vs baseline: 1.2195x; 1.2195x over previous
//
#include <hip/hip_runtime.h>
#include <math.h>

#define EPS 1e-8f

constexpr int B = 64;
constexpr int N = 65536;
constexpr int M = 64;
constexpr int D = 256;
constexpr int A = M + 6; // 70

typedef float vfloat4 __attribute__((ext_vector_type(4)));

// ---- workspace layout (in floats) ----
constexpr size_t OFF_KN   = 0;                               // [B*M]
constexpr size_t OFF_SCAL = OFF_KN + (size_t)B * M;          // [B*8]
constexpr size_t OFF_E    = OFF_SCAL + (size_t)B * 8;        // [B*N]  e = exp(beta*sim)
constexpr size_t OFF_ZP   = OFF_E + (size_t)B * N;           // [B*64] Z partials
constexpr size_t OFF_SP   = OFF_ZP + (size_t)B * 64;         // [B*64] wp-sum partials
constexpr size_t OFF_RP   = OFF_SP + (size_t)B * 64;         // [B*64*M] read partials
// total ~ 4.48M floats ~ 17.9 MB

__device__ __forceinline__ float softplusf(float x) {
    return (x > 20.0f) ? x : log1pf(expf(x));
}

// K1: a = emb @ W + b ; derive kn, beta, g, s, gamma. One block per b.
__global__ void k1_controller(const float* __restrict__ emb,
                              const float* __restrict__ Wm,
                              const float* __restrict__ bias,
                              float* __restrict__ kn,
                              float* __restrict__ scal) {
    int b = blockIdx.x;
    int t = threadIdx.x; // 256
    __shared__ float se[D];
    __shared__ float sa[A];
    __shared__ float snorm;
    se[t] = emb[(size_t)b * D + t];
    __syncthreads();
    if (t < A) {
        float acc = bias[t];
        for (int d = 0; d < D; ++d) acc += se[d] * Wm[(size_t)d * A + t];
        sa[t] = acc;
    }
    __syncthreads();
    if (t == 0) {
        float s = 0.f;
        for (int j = 0; j < M; ++j) s += sa[j] * sa[j];
        snorm = sqrtf(s) + EPS;
        float beta = softplusf(sa[M]);
        float g = 1.f / (1.f + expf(-sa[M + 1]));
        float s0 = sa[M + 2], s1 = sa[M + 3], s2 = sa[M + 4];
        float mx = fmaxf(s0, fmaxf(s1, s2));
        float e0 = expf(s0 - mx), e1 = expf(s1 - mx), e2 = expf(s2 - mx);
        float Zs = e0 + e1 + e2;
        float gamma = 1.f + softplusf(sa[M + 5]);
        scal[b * 8 + 0] = beta;
        scal[b * 8 + 1] = g;
        scal[b * 8 + 2] = e0 / Zs;
        scal[b * 8 + 3] = e1 / Zs;
        scal[b * 8 + 4] = e2 / Zs;
        scal[b * 8 + 5] = gamma;
    }
    __syncthreads();
    if (t < M) kn[b * M + t] = sa[t] / snorm;
}

// K2: e[b,n] = exp(beta * cos_sim(kn, mem_row)); block partial sums -> zpart.
// |beta*sim| <= beta (cosine), so no max-subtraction needed.
__global__ void k2_sim(const float* __restrict__ mem,
                       const float* __restrict__ kn,
                       const float* __restrict__ scal,
                       float* __restrict__ e,
                       float* __restrict__ zpart) {
    const int ROWS = 1024;
    int b = blockIdx.y;
    int base = blockIdx.x * ROWS;
    int t = threadIdx.x; // 256
    int gid = t >> 4, q = t & 15;
    float beta = scal[b * 8 + 0];
    const vfloat4 knq = reinterpret_cast<const vfloat4*>(kn + (size_t)b * M)[q];
    const vfloat4* mrow = reinterpret_cast<const vfloat4*>(mem + (size_t)b * N * M);
    float* eb = e + (size_t)b * N;
    float lsum = 0.f;
    #pragma unroll 8
    for (int r = gid; r < ROWS; r += 16) {
        int n = base + r;
        vfloat4 v = __builtin_nontemporal_load(&mrow[(size_t)n * 16 + q]);
        float dot = v.x * knq.x + v.y * knq.y + v.z * knq.z + v.w * knq.w;
        float nrm = v.x * v.x + v.y * v.y + v.z * v.z + v.w * v.w;
        #pragma unroll
        for (int msk = 8; msk >= 1; msk >>= 1) {
            dot += __shfl_xor(dot, msk);
            nrm += __shfl_xor(nrm, msk);
        }
        float ev = expf(beta * (dot / (sqrtf(nrm) + EPS)));
        if (q == 0) { eb[n] = ev; lsum += ev; }
    }
    __shared__ float red[16];
    if (q == 0) red[gid] = lsum;
    __syncthreads();
    if (t == 0) {
        float s = 0.f;
        #pragma unroll
        for (int i = 0; i < 16; ++i) s += red[i];
        zpart[b * 64 + blockIdx.x] = s;
    }
}

// K45: phase 1 computes wp (stencil+pow, unnormalized) for this block's 1024 rows
// into LDS + wout (vectorized). Phase 2 streams mem once: read partials += wp*row.
__global__ void k45_fused(const float* __restrict__ mem,
                          const float* __restrict__ e,
                          const float* __restrict__ wprev,
                          const float* __restrict__ scal,
                          const float* __restrict__ zpart,
                          float* __restrict__ wout,
                          float* __restrict__ spart,
                          float* __restrict__ readpart) {
    const int ROWS = 1024;
    int b = blockIdx.y;
    int bx = blockIdx.x; // 64
    int base = bx * ROWS;
    int t = threadIdx.x; // 256
    int gid = t >> 4, q = t & 15;

    __shared__ float s_wp[ROWS];
    __shared__ float red[256];
    __shared__ float sacc[16][64];

    float Z = 0.f;
    const float* zp = zpart + b * 64;
    #pragma unroll
    for (int i = 0; i < 64; ++i) Z += zp[i];
    float g   = scal[b * 8 + 1];
    float s0  = scal[b * 8 + 2];
    float s1  = scal[b * 8 + 3];
    float s2  = scal[b * 8 + 4];
    float gam = scal[b * 8 + 5];
    float c1 = g / Z;
    float c2 = 1.f - g;

    const float* eb = e + (size_t)b * N;
    const float* wb = wprev + (size_t)b * N;
    float* wo = wout + (size_t)b * N;

    // ---- phase 1: wp for rows [base, base+1024), 4 rows/thread ----
    {
        int n0 = base + t * 4;
        vfloat4 e4 = *reinterpret_cast<const vfloat4*>(eb + n0);
        vfloat4 w4 = *reinterpret_cast<const vfloat4*>(wb + n0);
        int nm = (n0 - 1) & (N - 1);
        int np = (n0 + 4) & (N - 1);
        float em = eb[nm], ep = eb[np];
        float wm = wb[nm], wpp = wb[np];
        float wgm = c1 * em   + c2 * wm;
        float wg0 = c1 * e4.x + c2 * w4.x;
        float wg1 = c1 * e4.y + c2 * w4.y;
        float wg2 = c1 * e4.z + c2 * w4.z;
        float wg3 = c1 * e4.w + c2 * w4.w;
        float wg4 = c1 * ep   + c2 * wpp;
        float p0 = powf(s0 * wgm + s1 * wg0 + s2 * wg1, gam);
        float p1 = powf(s0 * wg0 + s1 * wg1 + s2 * wg2, gam);
        float p2 = powf(s0 * wg1 + s1 * wg2 + s2 * wg3, gam);
        float p3 = powf(s0 * wg2 + s1 * wg3 + s2 * wg4, gam);
        s_wp[t * 4 + 0] = p0;
        s_wp[t * 4 + 1] = p1;
        s_wp[t * 4 + 2] = p2;
        s_wp[t * 4 + 3] = p3;
        vfloat4 pv; pv.x = p0; pv.y = p1; pv.z = p2; pv.w = p3;
        *reinterpret_cast<vfloat4*>(wo + n0) = pv;
        red[t] = (p0 + p1) + (p2 + p3);
    }
    __syncthreads();

    // ---- phase 2: stream mem, accumulate wp * row ----
    const vfloat4* mrow = reinterpret_cast<const vfloat4*>(mem + (size_t)b * N * M);
    vfloat4 acc = (vfloat4)0.f;
    #pragma unroll 8
    for (int r = gid; r < ROWS; r += 16) {
        float wp = s_wp[r];
        vfloat4 v = __builtin_nontemporal_load(&mrow[(size_t)(base + r) * 16 + q]);
        acc.x += wp * v.x;
        acc.y += wp * v.y;
        acc.z += wp * v.z;
        acc.w += wp * v.w;
    }
    sacc[gid][q * 4 + 0] = acc.x;
    sacc[gid][q * 4 + 1] = acc.y;
    sacc[gid][q * 4 + 2] = acc.z;
    sacc[gid][q * 4 + 3] = acc.w;
    __syncthreads();
    if (t < 64) {
        float s = 0.f;
        #pragma unroll
        for (int g2 = 0; g2 < 16; ++g2) s += sacc[g2][t];
        readpart[((size_t)b * 64 + bx) * 64 + t] = s;
    }
    // spart = sum of wp over this block's rows
    for (int k = 128; k >= 1; k >>= 1) {
        if (t < k) red[t] += red[t + k];
        __syncthreads();
    }
    if (t == 0) spart[b * 64 + bx] = red[0];
}

// K67: bx<64: w *= invS (float4). bx==64: read[b,m] = sum(partials)*invS.
__global__ void k67_epilogue(float* __restrict__ wout,
                             const float* __restrict__ spart,
                             const float* __restrict__ readpart,
                             float* __restrict__ readout) {
    int b = blockIdx.y;
    int bx = blockIdx.x; // 0..64
    int t = threadIdx.x; // 256
    float S = 0.f;
    const float* sp = spart + b * 64;
    #pragma unroll
    for (int i = 0; i < 64; ++i) S += sp[i];
    float invS = 1.f / (S + EPS);
    if (bx < 64) {
        size_t idx = (size_t)b * (N / 4) + (size_t)bx * 256 + t;
        vfloat4* w4 = reinterpret_cast<vfloat4*>(wout);
        vfloat4 v = w4[idx];
        v.x *= invS; v.y *= invS; v.z *= invS; v.w *= invS;
        w4[idx] = v;
    } else if (t < 64) {
        float s = 0.f;
        #pragma unroll
        for (int kb = 0; kb < 64; ++kb) s += readpart[((size_t)b * 64 + kb) * 64 + t];
        readout[b * 64 + t] = s * invS;
    }
}

extern "C" void kernel_launch(void* const* d_in, const int* in_sizes, int n_in,
                              void* d_out, int out_size, void* d_ws, size_t ws_size,
                              hipStream_t stream) {
    const float* emb   = (const float*)d_in[0];
    const float* wprev = (const float*)d_in[1];
    const float* mem   = (const float*)d_in[2];
    const float* Wm    = (const float*)d_in[3];
    const float* bias  = (const float*)d_in[4];

    float* out = (float*)d_out;
    float* readout = out;                 // [B, M]
    float* wout    = out + (size_t)B * M; // [B, N]

    float* ws = (float*)d_ws;
    float* kn   = ws + OFF_KN;
    float* scal = ws + OFF_SCAL;
    float* e    = ws + OFF_E;
    float* zp   = ws + OFF_ZP;
    float* sp   = ws + OFF_SP;
    float* rp   = ws + OFF_RP;

    k1_controller<<<dim3(B), dim3(256), 0, stream>>>(emb, Wm, bias, kn, scal);
    k2_sim<<<dim3(64, B), dim3(256), 0, stream>>>(mem, kn, scal, e, zp);
    k45_fused<<<dim3(64, B), dim3(256), 0, stream>>>(mem, e, wprev, scal, zp,
                                                     wout, sp, rp);
    k67_epilogue<<<dim3(65, B), dim3(256), 0, stream>>>(wout, sp, rp, readout);
}